// Round 10
// baseline (102.057 us; speedup 1.0000x reference)
//
#include <hip/hip_runtime.h>

// Gaussian-kernel MMD loss, N=M=8192, D=2 — 4 plain launches:
//   prep (means/constants) -> sort (bucket x-sort both clouds) ->
//   main (2080 static 256x256 tiles w/ quad skip) -> final.
// loss = mean(k_bb) + mean(k_tt) - 2*mean(k_bt), k = exp(-||x-y||^2/(2 s^2))
// - Coords pre-scaled by exp(log_scale)*sqrt(inv2s2*log2e); cross-shift
//   (mean_b - mean_t) folded into stored base coords (cancels in bb dists).
// - R9 result: wave64 v_exp_f32 ~30 cy issue -> kernel is trans-issue-bound
//   (R8 fits 8 waves/SIMD x 32 q x 240 cy = 25.6 us). Poly-exp2 on VALU
//   regressed (scalarized, ~15 cy/pair). Only exp-COUNT reduction helps:
// - Both clouds bucket-sorted by x. Pairs with scaled |dx| > sqrt(40)
//   contribute < 2^-40 (aggregate < 1e-9 << 4.7e-6 threshold). Per col-quad
//   (qlo,qhi) staged in LDS; wave-uniform compare vs wave row-range skips
//   3 ds_read_b128 + 8 exps. Expected survival ~0.45.
// - Tiles 256x256, 2 adjacent rows/thread (wave rows = 128 consecutive
//   sorted x -> tight range), half-block col split. Sym terms: upper
//   triangle, off-diag weight 2, diag per-pair masked (2/1/0).
// - Tile index = (bid*997) % 2080 to spread busy tiles across CUs.

#define BLOCK 256
#define NT_CROSS 1024
#define NT_TOT   2080
#define LOG2E  1.4426950408889634f
#define NBUCK  512
#define BXMIN  (-64.0f)
#define BSCALE 4.0f
#define CUT    6.32455532f   // sqrt(40) in scaled units

typedef float v2f __attribute__((ext_vector_type(2)));

struct Prep { float f0, f1, sh0, sh1; };

__device__ __forceinline__ float fexp2(float x) {
    return __builtin_amdgcn_exp2f(x);
}

// ---------------- prep: means, constants, zero slots ----------------
__global__ __launch_bounds__(1024) void prep_kernel(
    const float* __restrict__ base, const float* __restrict__ target,
    const float* __restrict__ log_sigma, const float* __restrict__ log_scale,
    int N, int M, Prep* __restrict__ pp, double* __restrict__ slots)
{
    __shared__ double mred[16][4];
    const int tid = threadIdx.x;
    if (tid < 64) slots[tid] = 0.0;

    double sbx = 0, sby = 0, stx = 0, sty = 0;
    const float4* b4 = (const float4*)base;
    const float4* t4 = (const float4*)target;
    for (int i = tid; i < (N >> 1); i += 1024) {
        float4 v = b4[i];
        sbx += (double)v.x + (double)v.z;
        sby += (double)v.y + (double)v.w;
    }
    for (int i = tid; i < (M >> 1); i += 1024) {
        float4 v = t4[i];
        stx += (double)v.x + (double)v.z;
        sty += (double)v.y + (double)v.w;
    }
    for (int off = 32; off; off >>= 1) {
        sbx += __shfl_down(sbx, off); sby += __shfl_down(sby, off);
        stx += __shfl_down(stx, off); sty += __shfl_down(sty, off);
    }
    if ((tid & 63) == 0) {
        mred[tid >> 6][0] = sbx; mred[tid >> 6][1] = sby;
        mred[tid >> 6][2] = stx; mred[tid >> 6][3] = sty;
    }
    __syncthreads();
    if (tid == 0) {
        double b0 = 0, b1 = 0, t0 = 0, t1 = 0;
        for (int k = 0; k < 16; ++k) {
            b0 += mred[k][0]; b1 += mred[k][1];
            t0 += mred[k][2]; t1 += mred[k][3];
        }
        float s0 = expf(log_scale[0]);
        float s1 = expf(log_scale[1]);
        float sigma = expf(log_sigma[0]);
        float inv2s2 = 1.0f / (2.0f * sigma * sigma);
        float sq = sqrtf(inv2s2 * LOG2E);
        float f0 = s0 * sq, f1 = s1 * sq;
        pp->f0 = f0; pp->f1 = f1;
        pp->sh0 = (float)(b0 / (double)N - t0 / (double)M) * f0;
        pp->sh1 = (float)(b1 / (double)N - t1 / (double)M) * f1;
    }
}

// ---------------- sort: bucket counting-sort by scaled x ----------------
// block 0: base (shift folded in), block 1: target. Outputs SoA xs/ys/cs.
__global__ __launch_bounds__(1024) void sort_kernel(
    const float* __restrict__ base, const float* __restrict__ target,
    int N, int M, const Prep* __restrict__ pp,
    float* __restrict__ xsB, float* __restrict__ ysB, float* __restrict__ csB,
    float* __restrict__ xsT, float* __restrict__ ysT, float* __restrict__ csT)
{
    __shared__ unsigned hist[NBUCK];
    __shared__ unsigned pref[NBUCK];
    __shared__ unsigned cnt[NBUCK];
    const int tid = threadIdx.x;
    const Prep p = *pp;
    const bool isB = (blockIdx.x == 0);
    const float2* src = (const float2*)(isB ? base : target);
    const int n = isB ? N : M;
    float* xs = isB ? xsB : xsT;
    float* ys = isB ? ysB : ysT;
    float* cs = isB ? csB : csT;
    const float shx = isB ? p.sh0 : 0.f;
    const float shy = isB ? p.sh1 : 0.f;

    for (int i = tid; i < NBUCK; i += 1024) { hist[i] = 0u; cnt[i] = 0u; }
    __syncthreads();
    for (int i = tid; i < n; i += 1024) {
        float2 a = src[i];
        float x = fmaf(a.x, p.f0, -shx);
        int b = (int)((x - BXMIN) * BSCALE);
        b = min(max(b, 0), NBUCK - 1);
        atomicAdd(&hist[b], 1u);
    }
    __syncthreads();
    if (tid < NBUCK) pref[tid] = hist[tid];
    __syncthreads();
    for (int off = 1; off < NBUCK; off <<= 1) {
        unsigned v = 0u;
        if (tid < NBUCK && tid >= off) v = pref[tid - off];
        __syncthreads();
        if (tid < NBUCK) pref[tid] += v;
        __syncthreads();
    }
    // pref is inclusive; start[b] = pref[b] - hist[b]
    for (int i = tid; i < n; i += 1024) {
        float2 a = src[i];
        float x = fmaf(a.x, p.f0, -shx);
        float y = fmaf(a.y, p.f1, -shy);
        int b = (int)((x - BXMIN) * BSCALE);
        b = min(max(b, 0), NBUCK - 1);
        unsigned pos = pref[b] - hist[b] + atomicAdd(&cnt[b], 1u);
        xs[pos] = x;
        ys[pos] = y;
        cs[pos] = -fmaf(x, x, y * y);
    }
}

// ---------------- main: 2080 static 256x256 tiles, quad skip ----------
__global__ __launch_bounds__(BLOCK, 8) void mmd_main(
    int N, int M,
    const float* __restrict__ xsB, const float* __restrict__ ysB,
    const float* __restrict__ csB,
    const float* __restrict__ xsT, const float* __restrict__ ysT,
    const float* __restrict__ csT,
    double* __restrict__ slots)
{
    __shared__ __align__(16) float tbx[256];
    __shared__ __align__(16) float tby[256];
    __shared__ __align__(16) float tbc[256];
    __shared__ __align__(8)  float2 qb[64];
    __shared__ double wredd[4];

    const int tid = threadIdx.x;
    const int t   = (int)(((long long)blockIdx.x * 997) % NT_TOT);

    const double wNN = 1.0 / ((double)N * (double)N);
    const double wMM = 1.0 / ((double)M * (double)M);
    const double wNM = -2.0 / ((double)N * (double)M);

    // ---- decode tile (R8-verified) ----
    int ib, jb, term;
    bool diag;
    const float* xA; const float* yA; const float* cA;
    const float* xB; const float* yB; const float* cB;
    double wt;
    if (t < NT_CROSS) {
        ib = t >> 5; jb = t & 31;
        xA = xsB; yA = ysB; cA = csB;
        xB = xsT; yB = ysT; cB = csT;
        wt = wNM; diag = false; term = 2;
    } else {
        const int u = t - NT_CROSS;
        term = (u >= 528) ? 1 : 0;
        const int v = u - term * 528;
        int r = (int)((65.0f - sqrtf(4225.0f - 8.0f * (float)v)) * 0.5f);
        r = min(max(r, 0), 31);
        while (r > 0 && (r * (65 - r)) / 2 > v) --r;
        while (r < 31 && ((r + 1) * (64 - r)) / 2 <= v) ++r;
        ib = r;
        jb = r + (v - (r * (65 - r)) / 2);
        diag = (jb == ib);
        if (term) { xA = xsT; yA = ysT; cA = csT; }
        else      { xA = xsB; yA = ysB; cA = csB; }
        xB = xA; yB = yA; cB = cA;
        wt = 2.0 * (term ? wMM : wNN);
    }
    const int i0 = ib * 256, j0 = jb * 256;

    // ---- stage B columns + per-quad x bounds ----
    tbx[tid] = xB[j0 + tid];
    tby[tid] = yB[j0 + tid];
    tbc[tid] = cB[j0 + tid];
    if (tid < 64) {
        float4 q4 = ((const float4*)(xB + j0))[tid];
        float qlo = fminf(fminf(q4.x, q4.y), fminf(q4.z, q4.w));
        float qhi = fmaxf(fmaxf(q4.x, q4.y), fmaxf(q4.z, q4.w));
        qb[tid] = make_float2(qlo, qhi);
    }
    __syncthreads();

    // ---- per-thread rows: r0 = i0 + 2*(tid&127), r1 = r0+1 ----
    // (adjacent rows -> each wave covers 128 consecutive sorted x)
    const int u_  = tid & 127;
    const int r0  = i0 + 2 * u_;
    const int js  = (tid >> 7) * 128;

    float2 xr = ((const float2*)xA)[r0 >> 1];
    float2 yr = ((const float2*)yA)[r0 >> 1];
    float2 cr = ((const float2*)cA)[r0 >> 1];
    float ax2s[2] = { xr.x + xr.x, xr.y + xr.y };
    float ay2s[2] = { yr.x + yr.x, yr.y + yr.y };
    float A0s[2]  = { cr.x, cr.y };

    // wave row x-range (pre-expanded by CUT)
    float rmin = fminf(xr.x, xr.y);
    float rmax = fmaxf(xr.x, xr.y);
    for (int off = 32; off; off >>= 1) {
        rmin = fminf(rmin, __shfl_xor(rmin, off));
        rmax = fmaxf(rmax, __shfl_xor(rmax, off));
    }
    const float rminc = rmin - CUT;
    const float rmaxc = rmax + CUT;

    const float4* bx4 = (const float4*)(tbx + js);
    const float4* by4 = (const float4*)(tby + js);
    const float4* c4  = (const float4*)(tbc + js);
    const int qoff = js >> 2;

    double result;
    if (!diag) {
        v2f s00 = {0.f, 0.f}, s01 = {0.f, 0.f};
        v2f s10 = {0.f, 0.f}, s11 = {0.f, 0.f};
#pragma unroll 2
        for (int q = 0; q < 32; ++q) {
            float2 qr = qb[qoff + q];
            if (qr.x > rmaxc || qr.y < rminc) continue;   // wave-uniform skip
            float4 BX = bx4[q];
            float4 BY = by4[q];
            float4 C  = c4[q];
            v2f bxa = { BX.x, BX.y }, bxb = { BX.z, BX.w };
            v2f bya = { BY.x, BY.y }, byb = { BY.z, BY.w };
            v2f ca  = { C.x,  C.y  }, cb  = { C.z,  C.w  };
            {
                v2f A0v = { A0s[0], A0s[0] };
                v2f axv = { ax2s[0], ax2s[0] };
                v2f ayv = { ay2s[0], ay2s[0] };
                v2f ea = axv * bxa + (ayv * bya + (ca + A0v));
                v2f eb = axv * bxb + (ayv * byb + (cb + A0v));
                s00 += (v2f){ fexp2(ea.x), fexp2(ea.y) };
                s01 += (v2f){ fexp2(eb.x), fexp2(eb.y) };
            }
            {
                v2f A0v = { A0s[1], A0s[1] };
                v2f axv = { ax2s[1], ax2s[1] };
                v2f ayv = { ay2s[1], ay2s[1] };
                v2f ea = axv * bxa + (ayv * bya + (ca + A0v));
                v2f eb = axv * bxb + (ayv * byb + (cb + A0v));
                s10 += (v2f){ fexp2(ea.x), fexp2(ea.y) };
                s11 += (v2f){ fexp2(eb.x), fexp2(eb.y) };
            }
        }
        v2f st0 = s00 + s01;
        v2f st1 = s10 + s11;
        result = wt * ((double)(st0.x + st0.y) + (double)(st1.x + st1.y));
    } else {
        // weight 2 for col>row, 1 for col==row, 0 for col<row (= sge + sgt)
        float sge = 0.f, sgt = 0.f;
        const int jbase = j0 + js;
#pragma unroll 2
        for (int q = 0; q < 32; ++q) {
            float2 qr = qb[qoff + q];
            if (qr.x > rmaxc || qr.y < rminc) continue;
            float4 BX = bx4[q];
            float4 BY = by4[q];
            float4 C  = c4[q];
            const int j = jbase + 4 * q;
#pragma unroll
            for (int k = 0; k < 2; ++k) {
                const int row = r0 + k;
                float e0 = fmaf(ax2s[k], BX.x, fmaf(ay2s[k], BY.x, C.x + A0s[k]));
                float e1 = fmaf(ax2s[k], BX.y, fmaf(ay2s[k], BY.y, C.y + A0s[k]));
                float e2 = fmaf(ax2s[k], BX.z, fmaf(ay2s[k], BY.z, C.z + A0s[k]));
                float e3 = fmaf(ax2s[k], BX.w, fmaf(ay2s[k], BY.w, C.w + A0s[k]));
                float v0 = fexp2(e0), v1 = fexp2(e1);
                float v2 = fexp2(e2), v3 = fexp2(e3);
                sge += (j + 0 >= row) ? v0 : 0.f;  sgt += (j + 0 > row) ? v0 : 0.f;
                sge += (j + 1 >= row) ? v1 : 0.f;  sgt += (j + 1 > row) ? v1 : 0.f;
                sge += (j + 2 >= row) ? v2 : 0.f;  sgt += (j + 2 > row) ? v2 : 0.f;
                sge += (j + 3 >= row) ? v3 : 0.f;  sgt += (j + 3 > row) ? v3 : 0.f;
            }
        }
        result = (term ? wMM : wNN) * (double)(sge + sgt);
    }

    // ---- block reduce (f64), publish to spread slots ----
    for (int off = 32; off; off >>= 1) result += __shfl_down(result, off);
    if ((tid & 63) == 0) wredd[tid >> 6] = result;
    __syncthreads();
    if (tid == 0) {
        double s = wredd[0] + wredd[1] + wredd[2] + wredd[3];
        atomicAdd(&slots[blockIdx.x & 63], s);
    }
}

// ---------------- final: reduce 64 slots ----------------
__global__ void final_kernel(const double* __restrict__ slots,
                             float* __restrict__ out)
{
    const int tid = threadIdx.x;
    double s = slots[tid];
    for (int off = 32; off; off >>= 1) s += __shfl_down(s, off);
    if (tid == 0) out[0] = (float)s;
}

extern "C" void kernel_launch(void* const* d_in, const int* in_sizes, int n_in,
                              void* d_out, int out_size, void* d_ws, size_t ws_size,
                              hipStream_t stream)
{
    const float* base      = (const float*)d_in[0];
    const float* target    = (const float*)d_in[1];
    const float* log_sigma = (const float*)d_in[2];
    const float* log_scale = (const float*)d_in[3];
    float* out = (float*)d_out;

    int N = in_sizes[0] / 2;
    int M = in_sizes[1] / 2;

    char* ws = (char*)d_ws;
    Prep*   pp    = (Prep*)ws;                  // 16 B
    double* slots = (double*)(ws + 256);        // 64 doubles
    float*  arr   = (float*)(ws + 1024);        // sorted SoA arrays
    float* xsB = arr;
    float* ysB = xsB + N;
    float* csB = ysB + N;
    float* xsT = csB + N;
    float* ysT = xsT + M;
    float* csT = ysT + M;

    prep_kernel<<<1, 1024, 0, stream>>>(base, target, log_sigma, log_scale,
                                        N, M, pp, slots);
    sort_kernel<<<2, 1024, 0, stream>>>(base, target, N, M, pp,
                                        xsB, ysB, csB, xsT, ysT, csT);
    mmd_main<<<NT_TOT, BLOCK, 0, stream>>>(N, M, xsB, ysB, csB,
                                           xsT, ysT, csT, slots);
    final_kernel<<<1, 64, 0, stream>>>(slots, out);
}

// Round 11
// 98.919 us; speedup vs baseline: 1.0317x; 1.0317x over previous
//
#include <hip/hip_runtime.h>

// Gaussian-kernel MMD loss, N=M=8192, D=2 — 3 plain launches:
//   sort (bucket x-sort + means) -> main (3072 phase-strided blocks) -> final.
// loss = mean(k_bb) + mean(k_tt) - 2*mean(k_bt), k = exp(-||x-y||^2/(2 s^2))
// - Coords stored pre-scaled by exp(log_scale)*sqrt(inv2s2*log2e), x-sorted
//   (bucket sort; any permutation is correct — sort quality only affects the
//   skip rate). Cross-term centering shift applied to A rows at compute time
//   (sort order is shift-invariant).
// - R9/R10 lessons: wave64 v_exp_f32 ~30 cy -> trans-issue-bound; only exp
//   COUNT matters. R10's contiguous tiles gave BINARY tile survival -> max-
//   loaded-SIMD tail ate the skip. Fix: block = (term, row-tile, col-PHASE);
//   block owns quads q == phase (mod 32) spread over the whole sorted range,
//   so all 32 phase-blocks of a row-tile have identical work.
// - Per-quad skip: quad (4 consecutive sorted cols) x-range vs wave row-range
//   (128 consecutive sorted rows) +- CUT. CUT^2=28: dropped mass <= ~7e-9
//   << 4.7e-6 threshold. Sym terms: quad all-below diag -> skip; all-above ->
//   weight 2 (with x-skip); straddle (~1 quad/wave) -> per-pair 2/1/0 mask.
// - Block partials -> 64 spread f64 atomic slots; tiny final kernel reduces.

#define BLOCK    256
#define NT_CROSS 1024
#define NT_TOT   3072
#define NBUCK    512
#define BXMIN    (-64.0f)
#define BSCALE   4.0f
#define CUT      5.2915026f   // sqrt(28)
#define LOG2E    1.4426950408889634f

typedef float v2f __attribute__((ext_vector_type(2)));

__device__ __forceinline__ float fexp2(float x) {
    return __builtin_amdgcn_exp2f(x);
}

// ---------------- sort: bucket x-sort + mean sums (2 blocks) ----------------
__global__ __launch_bounds__(1024) void sort_kernel(
    const float* __restrict__ base, const float* __restrict__ target,
    const float* __restrict__ log_sigma, const float* __restrict__ log_scale,
    int N, int M,
    float* __restrict__ xsB, float* __restrict__ ysB, float* __restrict__ csB,
    float* __restrict__ xsT, float* __restrict__ ysT, float* __restrict__ csT,
    double* __restrict__ msum, double* __restrict__ slots)
{
    __shared__ unsigned hist[NBUCK], pref[NBUCK], cnt[NBUCK];
    __shared__ double mred[16][2];
    const int tid = threadIdx.x;
    const bool isB = (blockIdx.x == 0);
    if (isB && tid < 64) slots[tid] = 0.0;

    const float sigma = expf(log_sigma[0]);
    const float sq = sqrtf((0.5f / (sigma * sigma)) * LOG2E);
    const float f0 = expf(log_scale[0]) * sq;
    const float f1 = expf(log_scale[1]) * sq;

    const float2* src = (const float2*)(isB ? base : target);
    const int n = isB ? N : M;
    float* xs = isB ? xsB : xsT;
    float* ys = isB ? ysB : ysT;
    float* cs = isB ? csB : csT;

    for (int i = tid; i < NBUCK; i += 1024) { hist[i] = 0u; cnt[i] = 0u; }
    __syncthreads();

    double sx = 0.0, sy = 0.0;
    for (int i = tid; i < n; i += 1024) {
        float2 a = src[i];
        float x = a.x * f0, y = a.y * f1;
        sx += (double)x; sy += (double)y;
        int b = min(max((int)((x - BXMIN) * BSCALE), 0), NBUCK - 1);
        atomicAdd(&hist[b], 1u);
    }
    for (int off = 32; off; off >>= 1) {
        sx += __shfl_down(sx, off);
        sy += __shfl_down(sy, off);
    }
    if ((tid & 63) == 0) { mred[tid >> 6][0] = sx; mred[tid >> 6][1] = sy; }
    __syncthreads();
    if (tid == 0) {
        double ax = 0, ay = 0;
        for (int k = 0; k < 16; ++k) { ax += mred[k][0]; ay += mred[k][1]; }
        msum[2 * blockIdx.x] = ax; msum[2 * blockIdx.x + 1] = ay;
    }

    if (tid < NBUCK) pref[tid] = hist[tid];
    __syncthreads();
    for (int off = 1; off < NBUCK; off <<= 1) {
        unsigned v = 0u;
        if (tid < NBUCK && tid >= off) v = pref[tid - off];
        __syncthreads();
        if (tid < NBUCK) pref[tid] += v;
        __syncthreads();
    }
    // pref inclusive; start[b] = pref[b] - hist[b]
    for (int i = tid; i < n; i += 1024) {
        float2 a = src[i];
        float x = a.x * f0, y = a.y * f1;
        int b = min(max((int)((x - BXMIN) * BSCALE), 0), NBUCK - 1);
        unsigned pos = pref[b] - hist[b] + atomicAdd(&cnt[b], 1u);
        xs[pos] = x;
        ys[pos] = y;
        cs[pos] = -fmaf(x, x, y * y);
    }
}

// ---------------- main: 3072 phase-strided blocks ----------------
__global__ __launch_bounds__(BLOCK, 8) void mmd_main(
    int N, int M,
    const float* __restrict__ xsB, const float* __restrict__ ysB,
    const float* __restrict__ csB,
    const float* __restrict__ xsT, const float* __restrict__ ysT,
    const float* __restrict__ csT,
    const double* __restrict__ msum, double* __restrict__ slots)
{
    __shared__ __align__(16) float tbx[256];
    __shared__ __align__(16) float tby[256];
    __shared__ __align__(16) float tbc[256];
    __shared__ __align__(8)  float2 qb[64];
    __shared__ double wredd[4];

    const int tid = threadIdx.x;
    const int t   = blockIdx.x;

    const double wNN = 1.0 / ((double)N * (double)N);
    const double wMM = 1.0 / ((double)M * (double)M);
    const double wNM = -2.0 / ((double)N * (double)M);

    // ---- decode: (sym?, term, row-tile, phase) ----
    int rt, phase, term;
    bool sym;
    const float *xA, *yA, *xB, *yB, *cB;
    double wt;                       // plain-path weight
    float shx = 0.f, shy = 0.f;
    if (t < NT_CROSS) {
        sym = false; term = 2;
        rt = t >> 5; phase = t & 31;
        xA = xsB; yA = ysB; xB = xsT; yB = ysT; cB = csT;
        wt = wNM;
        shx = (float)(msum[0] / (double)N - msum[2] / (double)M);
        shy = (float)(msum[1] / (double)N - msum[3] / (double)M);
    } else {
        sym = true;
        const int u = t - NT_CROSS;
        term = (u >= 1024) ? 1 : 0;
        const int v = u & 1023;
        rt = v >> 5; phase = v & 31;
        if (term) { xA = xsT; yA = ysT; xB = xsT; yB = ysT; cB = csT; }
        else      { xA = xsB; yA = ysB; xB = xsB; yB = ysB; cB = csB; }
        wt = 2.0 * (term ? wMM : wNN);
    }
    const int i0  = rt * 256;
    const int jq0 = 4 * phase;       // global col index of quad 0's first col

    // ---- stage 64 strided quads (SoA) + per-quad x bounds ----
    {
        const int g = tid & 63;
        const int addr = jq0 + 128 * g;          // element index, 16B-aligned
        if (tid < 64) {
            float4 v4 = *(const float4*)(xB + addr);
            *(float4*)&tbx[4 * g] = v4;
            qb[g] = make_float2(fminf(fminf(v4.x, v4.y), fminf(v4.z, v4.w)),
                                fmaxf(fmaxf(v4.x, v4.y), fmaxf(v4.z, v4.w)));
        } else if (tid < 128) {
            *(float4*)&tby[4 * g] = *(const float4*)(yB + addr);
        } else if (tid < 192) {
            *(float4*)&tbc[4 * g] = *(const float4*)(cB + addr);
        }
    }
    __syncthreads();

    // ---- per-thread rows r0, r0+1 (wave = 128 consecutive sorted rows) ----
    const int u_    = tid & 127;
    const int r0    = i0 + 2 * u_;
    const int qoff  = (tid >> 7) * 32;
    const int wr_lo = i0 + ((tid >> 6) & 1) * 128;
    const int wr_hi = wr_lo + 127;

    float2 xr = *(const float2*)(xA + r0);
    float2 yr = *(const float2*)(yA + r0);
    const float axr0 = xr.x - shx, axr1 = xr.y - shx;
    const float ayr0 = yr.x - shy, ayr1 = yr.y - shy;
    const float ax2s[2] = { axr0 + axr0, axr1 + axr1 };
    const float ay2s[2] = { ayr0 + ayr0, ayr1 + ayr1 };
    const float A0s[2]  = { -fmaf(axr0, axr0, ayr0 * ayr0),
                            -fmaf(axr1, axr1, ayr1 * ayr1) };

    float rmin = fminf(axr0, axr1), rmax = fmaxf(axr0, axr1);
    for (int off = 32; off; off >>= 1) {
        rmin = fminf(rmin, __shfl_xor(rmin, off));
        rmax = fmaxf(rmax, __shfl_xor(rmax, off));
    }
    const float rminc = rmin - CUT, rmaxc = rmax + CUT;

    v2f s00 = {0.f, 0.f}, s01 = {0.f, 0.f};
    v2f s10 = {0.f, 0.f}, s11 = {0.f, 0.f};
    float sge = 0.f, sgt = 0.f;

    if (!sym) {
#pragma unroll 2
        for (int m = 0; m < 32; ++m) {
            const int qi = qoff + m;
            float2 qr = qb[qi];
            if (qr.x > rmaxc || qr.y < rminc) continue;   // wave-uniform skip
            float4 BX = *(const float4*)&tbx[4 * qi];
            float4 BY = *(const float4*)&tby[4 * qi];
            float4 C  = *(const float4*)&tbc[4 * qi];
            v2f bxa = { BX.x, BX.y }, bxb = { BX.z, BX.w };
            v2f bya = { BY.x, BY.y }, byb = { BY.z, BY.w };
            v2f ca  = { C.x,  C.y  }, cb  = { C.z,  C.w  };
            {
                v2f A0v = { A0s[0], A0s[0] };
                v2f axv = { ax2s[0], ax2s[0] };
                v2f ayv = { ay2s[0], ay2s[0] };
                v2f ea = axv * bxa + (ayv * bya + (ca + A0v));
                v2f eb = axv * bxb + (ayv * byb + (cb + A0v));
                s00 += (v2f){ fexp2(ea.x), fexp2(ea.y) };
                s01 += (v2f){ fexp2(eb.x), fexp2(eb.y) };
            }
            {
                v2f A0v = { A0s[1], A0s[1] };
                v2f axv = { ax2s[1], ax2s[1] };
                v2f ayv = { ay2s[1], ay2s[1] };
                v2f ea = axv * bxa + (ayv * bya + (ca + A0v));
                v2f eb = axv * bxb + (ayv * byb + (cb + A0v));
                s10 += (v2f){ fexp2(ea.x), fexp2(ea.y) };
                s11 += (v2f){ fexp2(eb.x), fexp2(eb.y) };
            }
        }
    } else {
#pragma unroll 2
        for (int m = 0; m < 32; ++m) {
            const int qi = qoff + m;
            const int jq = jq0 + 128 * qi;
            if (jq + 3 < wr_lo) continue;                 // below diagonal band
            const bool mask = (jq <= wr_hi);              // straddles diag band
            float2 qr = qb[qi];
            if (!mask && (qr.x > rmaxc || qr.y < rminc)) continue;
            float4 BX = *(const float4*)&tbx[4 * qi];
            float4 BY = *(const float4*)&tby[4 * qi];
            float4 C  = *(const float4*)&tbc[4 * qi];
            if (!mask) {
                v2f bxa = { BX.x, BX.y }, bxb = { BX.z, BX.w };
                v2f bya = { BY.x, BY.y }, byb = { BY.z, BY.w };
                v2f ca  = { C.x,  C.y  }, cb  = { C.z,  C.w  };
                {
                    v2f A0v = { A0s[0], A0s[0] };
                    v2f axv = { ax2s[0], ax2s[0] };
                    v2f ayv = { ay2s[0], ay2s[0] };
                    v2f ea = axv * bxa + (ayv * bya + (ca + A0v));
                    v2f eb = axv * bxb + (ayv * byb + (cb + A0v));
                    s00 += (v2f){ fexp2(ea.x), fexp2(ea.y) };
                    s01 += (v2f){ fexp2(eb.x), fexp2(eb.y) };
                }
                {
                    v2f A0v = { A0s[1], A0s[1] };
                    v2f axv = { ax2s[1], ax2s[1] };
                    v2f ayv = { ay2s[1], ay2s[1] };
                    v2f ea = axv * bxa + (ayv * bya + (ca + A0v));
                    v2f eb = axv * bxb + (ayv * byb + (cb + A0v));
                    s10 += (v2f){ fexp2(ea.x), fexp2(ea.y) };
                    s11 += (v2f){ fexp2(eb.x), fexp2(eb.y) };
                }
            } else {
                // per-pair: weight 2 for j>row, 1 for j==row, 0 for j<row
#pragma unroll
                for (int k = 0; k < 2; ++k) {
                    const int row = r0 + k;
                    float e0 = fmaf(ax2s[k], BX.x, fmaf(ay2s[k], BY.x, C.x + A0s[k]));
                    float e1 = fmaf(ax2s[k], BX.y, fmaf(ay2s[k], BY.y, C.y + A0s[k]));
                    float e2 = fmaf(ax2s[k], BX.z, fmaf(ay2s[k], BY.z, C.z + A0s[k]));
                    float e3 = fmaf(ax2s[k], BX.w, fmaf(ay2s[k], BY.w, C.w + A0s[k]));
                    float v0 = fexp2(e0), v1 = fexp2(e1);
                    float v2 = fexp2(e2), v3 = fexp2(e3);
                    sge += (jq + 0 >= row) ? v0 : 0.f;  sgt += (jq + 0 > row) ? v0 : 0.f;
                    sge += (jq + 1 >= row) ? v1 : 0.f;  sgt += (jq + 1 > row) ? v1 : 0.f;
                    sge += (jq + 2 >= row) ? v2 : 0.f;  sgt += (jq + 2 > row) ? v2 : 0.f;
                    sge += (jq + 3 >= row) ? v3 : 0.f;  sgt += (jq + 3 > row) ? v3 : 0.f;
                }
            }
        }
    }

    v2f st0 = s00 + s01, st1 = s10 + s11;
    double result = wt * ((double)(st0.x + st0.y) + (double)(st1.x + st1.y));
    if (sym) result += (term ? wMM : wNN) * (double)(sge + sgt);

    // ---- block reduce (f64), publish to spread slots ----
    for (int off = 32; off; off >>= 1) result += __shfl_down(result, off);
    if ((tid & 63) == 0) wredd[tid >> 6] = result;
    __syncthreads();
    if (tid == 0) {
        double s = wredd[0] + wredd[1] + wredd[2] + wredd[3];
        atomicAdd(&slots[t & 63], s);
    }
}

// ---------------- final: reduce 64 slots ----------------
__global__ void final_kernel(const double* __restrict__ slots,
                             float* __restrict__ out)
{
    const int tid = threadIdx.x;
    double s = slots[tid];
    for (int off = 32; off; off >>= 1) s += __shfl_down(s, off);
    if (tid == 0) out[0] = (float)s;
}

extern "C" void kernel_launch(void* const* d_in, const int* in_sizes, int n_in,
                              void* d_out, int out_size, void* d_ws, size_t ws_size,
                              hipStream_t stream)
{
    const float* base      = (const float*)d_in[0];
    const float* target    = (const float*)d_in[1];
    const float* log_sigma = (const float*)d_in[2];
    const float* log_scale = (const float*)d_in[3];
    float* out = (float*)d_out;

    int N = in_sizes[0] / 2;
    int M = in_sizes[1] / 2;

    char* ws = (char*)d_ws;
    double* msum  = (double*)ws;                 // 4 doubles
    double* slots = (double*)(ws + 64);          // 64 doubles
    float*  arr   = (float*)(ws + 1024);
    float* xsB = arr;
    float* ysB = xsB + N;
    float* csB = ysB + N;
    float* xsT = csB + N;
    float* ysT = xsT + M;
    float* csT = ysT + M;

    sort_kernel<<<2, 1024, 0, stream>>>(base, target, log_sigma, log_scale,
                                        N, M, xsB, ysB, csB, xsT, ysT, csT,
                                        msum, slots);
    mmd_main<<<NT_TOT, BLOCK, 0, stream>>>(N, M, xsB, ysB, csB,
                                           xsT, ysT, csT, msum, slots);
    final_kernel<<<1, 64, 0, stream>>>(slots, out);
}